// Round 2
// baseline (498.746 us; speedup 1.0000x reference)
//
#include <hip/hip_runtime.h>
#include <math.h>

#define HIDDEN 128
#define IDIM   50000
#define STEPS  100

// ws layout (float offsets)
#define WS_E1H  0        // 256   e1 partials [2][128]
#define WS_CH   256      // 256   c  partials [2][128]
#define WS_M    512      // 16384 M = W_enc@W_dec (128x128)
#define WS_P    16896    // 49152 P = W_ih@M (384x128)
#define WS_Q    66048    // 384   q = W_ih@(c+b_enc)+b_ih
#define WS_IG1  66432    // 384   ig1 = W_ih@(e1+b_enc)+b_ih
#define WS_HT   66816    // 16384 H_T[i][k] (128x128, cols 0..99 used)

__device__ __forceinline__ float sigmoidf_(float x){ return 1.0f/(1.0f+expf(-x)); }

// e1p[half][r] = dot(W_enc[r, half*25000 : +25000], x0); cp likewise vs b_dec.
// 256 blocks (2 per row), direct store of block partial (no atomics, no zero-pass).
__global__ __launch_bounds__(256) void k_enc(const float* __restrict__ W_enc,
    const float* __restrict__ x0, const float* __restrict__ b_dec,
    float* __restrict__ ws)
{
  const int r    = blockIdx.x >> 1;
  const int half = blockIdx.x & 1;
  const float4* wr = (const float4*)(W_enc + (size_t)r*IDIM + half*25000);
  const float4* xv = (const float4*)(x0   + half*25000);
  const float4* bv = (const float4*)(b_dec + half*25000);
  float s0 = 0.f, s1 = 0.f;
  for (int i = threadIdx.x; i < 6250; i += 256){
    float4 w = wr[i]; float4 a = xv[i]; float4 b = bv[i];
    s0 += w.x*a.x + w.y*a.y + w.z*a.z + w.w*a.w;
    s1 += w.x*b.x + w.y*b.y + w.z*b.z + w.w*b.w;
  }
  __shared__ float r0[256], r1[256];
  r0[threadIdx.x] = s0; r1[threadIdx.x] = s1;
  __syncthreads();
  for (int off = 128; off > 0; off >>= 1){
    if (threadIdx.x < off){
      r0[threadIdx.x] += r0[threadIdx.x+off];
      r1[threadIdx.x] += r1[threadIdx.x+off];
    }
    __syncthreads();
  }
  if (threadIdx.x == 0){
    ws[WS_E1H + half*128 + r] = r0[0];
    ws[WS_CH  + half*128 + r] = r1[0];
  }
}

// M partials: 500 blocks, each K-chunk of 100; 128x128 tile, 8x8 micro-tile.
// Partials land in scratch (= d_out, free until k_decode).
__global__ __launch_bounds__(256) void k_gemmM(const float* __restrict__ W_enc,
    const float* __restrict__ W_dec, float* __restrict__ scratch)
{
  __shared__ __align__(16) float As[4][128];
  __shared__ __align__(16) float Bs[4][128];
  const int t  = threadIdx.x;
  const int tx = t & 15, ty = t >> 4;
  const int d0 = blockIdx.x * 100;
  float acc[8][8];
  #pragma unroll
  for (int p = 0; p < 8; p++)
    #pragma unroll
    for (int q = 0; q < 8; q++) acc[p][q] = 0.f;

  for (int k0 = 0; k0 < 100; k0 += 4){
    __syncthreads();
    if (t < 128){
      float4 w = *(const float4*)(W_enc + (size_t)t*IDIM + d0 + k0);
      As[0][t] = w.x; As[1][t] = w.y; As[2][t] = w.z; As[3][t] = w.w;
    } else {
      int u = t - 128; int kk = u >> 5, g = u & 31;
      *(float4*)&Bs[kk][g*4] = *(const float4*)(W_dec + (size_t)(d0+k0+kk)*HIDDEN + g*4);
    }
    __syncthreads();
    #pragma unroll
    for (int kk = 0; kk < 4; kk++){
      float4 alo = *(const float4*)&As[kk][ty*8];
      float4 ahi = *(const float4*)&As[kk][ty*8+4];
      float4 blo = *(const float4*)&Bs[kk][tx*8];
      float4 bhi = *(const float4*)&Bs[kk][tx*8+4];
      float a[8] = {alo.x,alo.y,alo.z,alo.w,ahi.x,ahi.y,ahi.z,ahi.w};
      float b[8] = {blo.x,blo.y,blo.z,blo.w,bhi.x,bhi.y,bhi.z,bhi.w};
      #pragma unroll
      for (int p = 0; p < 8; p++)
        #pragma unroll
        for (int q = 0; q < 8; q++) acc[p][q] += a[p]*b[q];
    }
  }
  float* outp = scratch + (size_t)blockIdx.x * 16384;
  #pragma unroll
  for (int p = 0; p < 8; p++){
    #pragma unroll
    for (int q = 0; q < 8; q += 4){
      *(float4*)&outp[(ty*8+p)*128 + tx*8 + q] =
        make_float4(acc[p][q], acc[p][q+1], acc[p][q+2], acc[p][q+3]);
    }
  }
}

// Sum 500 partials -> M. 64 blocks x 256 threads; 10 accumulators for load ILP.
__global__ __launch_bounds__(256) void k_reduceM(const float* __restrict__ scratch,
    float* __restrict__ Mout)
{
  const int idx = blockIdx.x * 256 + threadIdx.x;
  float s[10];
  #pragma unroll
  for (int u = 0; u < 10; u++) s[u] = 0.f;
  for (int p = 0; p < 500; p += 10){
    #pragma unroll
    for (int u = 0; u < 10; u++)
      s[u] += scratch[(size_t)(p+u)*16384 + idx];
  }
  float t0 = (s[0]+s[1]) + (s[2]+s[3]);
  float t1 = (s[4]+s[5]) + (s[6]+s[7]);
  Mout[idx] = t0 + t1 + (s[8]+s[9]);
}

// P[r,:] = W_ih[r,:]@M ; q[r] = W_ih[r,:]@(c+b_enc)+b_ih[r];
// ig1[r] = W_ih[r,:]@(e1+b_enc)+b_ih[r]. 384 blocks x 128 threads.
__global__ __launch_bounds__(128) void k_smallP(const float* __restrict__ W_ih,
    const float* __restrict__ b_ih, const float* __restrict__ b_enc,
    const float* __restrict__ ws, const float* __restrict__ M,
    float* __restrict__ P, float* __restrict__ q, float* __restrict__ ig1)
{
  const int r = blockIdx.x, j = threadIdx.x;
  const float* wr = W_ih + (size_t)r * HIDDEN;
  float acc = 0.f;
  for (int k = 0; k < HIDDEN; k++) acc += wr[k] * M[k*HIDDEN + j];
  P[(size_t)r*HIDDEN + j] = acc;
  const float wj = wr[j];
  float cj  = ws[WS_CH  + j] + ws[WS_CH  + 128 + j];
  float e1j = ws[WS_E1H + j] + ws[WS_E1H + 128 + j];
  float t0 = wj * (cj  + b_enc[j]);
  float t1 = wj * (e1j + b_enc[j]);
  __shared__ float r0[128], r1[128];
  r0[j] = t0; r1[j] = t1;
  __syncthreads();
  for (int off = 64; off > 0; off >>= 1){
    if (j < off){ r0[j] += r0[j+off]; r1[j] += r1[j+off]; }
    __syncthreads();
  }
  if (j == 0){
    q[r]   = r0[0] + b_ih[r];
    ig1[r] = r1[0] + b_ih[r];
  }
}

// The sequential recurrence. 1 block, 768 threads: thread t owns row t of
// [P; W_hh] in 128 VGPRs. h broadcast from LDS; 2 barriers/step; 99 steps.
// __launch_bounds__(768, 3): 12 waves = exactly 3/SIMD -> VGPR cap ~170,
// enough to keep wv[32] (128 VGPRs) resident. R1's missing 2nd arg made the
// compiler target 6 waves/SIMD (80 VGPRs) and spill the whole array.
// h_1 computed inline from ig1 (h_0 = 0 => hg terms vanish).
__global__ __launch_bounds__(768, 3) void k_recur(const float* __restrict__ P,
    const float* __restrict__ W_hh, const float* __restrict__ q,
    const float* __restrict__ b_n, const float* __restrict__ ig1,
    float* __restrict__ H_T)
{
  const int t = threadIdx.x;
  float4 wv[32];
  float qq;
  if (t < 384){
    const float4* src = (const float4*)(P + (size_t)t * HIDDEN);
    #pragma unroll
    for (int j = 0; j < 32; j++) wv[j] = src[j];
    qq = q[t];
  } else {
    const float4* src = (const float4*)(W_hh + (size_t)(t-384) * HIDDEN);
    #pragma unroll
    for (int j = 0; j < 32; j++) wv[j] = src[j];
    qq = 0.f;
  }
  __shared__ __align__(16) float h[HIDDEN];
  __shared__ float z[768];
  __shared__ float bn[HIDDEN];
  if (t < HIDDEN){
    float bnv   = b_n[t];
    float reset = sigmoidf_(ig1[t]);
    float inp   = sigmoidf_(ig1[128+t]);
    float nw    = tanhf(ig1[256+t] + reset * bnv);
    float h1    = nw + inp * (0.f - nw);
    bn[t] = bnv;
    h[t]  = h1;
    H_T[(size_t)t*HIDDEN] = h1;
  }
  __syncthreads();
  for (int k = 1; k < STEPS; k++){
    float a0 = qq, a1 = 0.f, a2 = 0.f, a3 = 0.f;
    const float4* h4 = (const float4*)h;
    #pragma unroll
    for (int j = 0; j < 32; j += 4){
      float4 h0 = h4[j+0];
      a0 += wv[j+0].x*h0.x + wv[j+0].y*h0.y + wv[j+0].z*h0.z + wv[j+0].w*h0.w;
      float4 h1v = h4[j+1];
      a1 += wv[j+1].x*h1v.x + wv[j+1].y*h1v.y + wv[j+1].z*h1v.z + wv[j+1].w*h1v.w;
      float4 h2 = h4[j+2];
      a2 += wv[j+2].x*h2.x + wv[j+2].y*h2.y + wv[j+2].z*h2.z + wv[j+2].w*h2.w;
      float4 h3 = h4[j+3];
      a3 += wv[j+3].x*h3.x + wv[j+3].y*h3.y + wv[j+3].z*h3.z + wv[j+3].w*h3.w;
    }
    z[t] = (a0+a1) + (a2+a3);
    __syncthreads();
    if (t < HIDDEN){
      float reset = sigmoidf_(z[t]       + z[384+t]);
      float inp   = sigmoidf_(z[128+t]   + z[512+t]);
      float nw    = tanhf(z[256+t] + reset*(z[640+t] + bn[t]));
      float hn    = nw + inp*(h[t] - nw);
      H_T[(size_t)t*HIDDEN + k] = hn;
      h[t] = hn;        // other threads read h only after the barrier below
    }
    __syncthreads();
  }
}

// X[k][d] = W_dec[d,:]@h_k + b_dec[d]; write samples/means/sigmas.
// Tile 64 d x 64 k, micro 4x4; H-tile in LDS, W_dec via L1; float4 stores.
__global__ __launch_bounds__(256) void k_decode(const float* __restrict__ W_dec,
    const float* __restrict__ b_dec, const float* __restrict__ H_T,
    float* __restrict__ out)
{
  __shared__ __align__(16) float Bs[128][68];
  const int t  = threadIdx.x;
  const int tx = t & 15, ty = t >> 4;
  const int d0 = blockIdx.x * 64;
  const int k0 = blockIdx.y * 64;

  // stage H_T[:, k0:k0+64] -> Bs (128 rows x 16 float4)
  for (int l = t; l < 2048; l += 256){
    int j = l >> 4, g = l & 15;
    *(float4*)&Bs[j][g*4] = *(const float4*)&H_T[(size_t)j*HIDDEN + k0 + g*4];
  }
  __syncthreads();

  const int d  = d0 + tx*4;               // always a multiple of 4
  const int dc = (d < IDIM) ? d : 0;      // clamp: garbage rows never stored
  const float* A0 = W_dec + (size_t)dc * HIDDEN;
  const float* A1 = A0 + HIDDEN;
  const float* A2 = A1 + HIDDEN;
  const float* A3 = A2 + HIDDEN;

  float acc[4][4];
  #pragma unroll
  for (int p = 0; p < 4; p++)
    #pragma unroll
    for (int q = 0; q < 4; q++) acc[p][q] = 0.f;

  for (int j0 = 0; j0 < HIDDEN; j0 += 4){
    float4 a0 = *(const float4*)(A0 + j0);
    float4 a1 = *(const float4*)(A1 + j0);
    float4 a2 = *(const float4*)(A2 + j0);
    float4 a3 = *(const float4*)(A3 + j0);
    #pragma unroll
    for (int jj = 0; jj < 4; jj++){
      float4 b = *(const float4*)&Bs[j0+jj][ty*4];
      float e0 = (jj==0)?a0.x:(jj==1)?a0.y:(jj==2)?a0.z:a0.w;
      float e1 = (jj==0)?a1.x:(jj==1)?a1.y:(jj==2)?a1.z:a1.w;
      float e2 = (jj==0)?a2.x:(jj==1)?a2.y:(jj==2)?a2.z:a2.w;
      float e3 = (jj==0)?a3.x:(jj==1)?a3.y:(jj==2)?a3.z:a3.w;
      acc[0][0] += e0*b.x; acc[0][1] += e0*b.y; acc[0][2] += e0*b.z; acc[0][3] += e0*b.w;
      acc[1][0] += e1*b.x; acc[1][1] += e1*b.y; acc[1][2] += e1*b.z; acc[1][3] += e1*b.w;
      acc[2][0] += e2*b.x; acc[2][1] += e2*b.y; acc[2][2] += e2*b.z; acc[2][3] += e2*b.w;
      acc[3][0] += e3*b.x; acc[3][1] += e3*b.y; acc[3][2] += e3*b.z; acc[3][3] += e3*b.w;
    }
  }

  if (d < IDIM){   // d multiple of 4 => d+3 <= 49999 whenever d < 50000
    float4 bd = *(const float4*)&b_dec[d];
    const size_t SO = (size_t)STEPS * IDIM;  // 5,000,000
    #pragma unroll
    for (int q = 0; q < 4; q++){
      int k = k0 + ty*4 + q;
      if (k < STEPS){
        float4 v = make_float4(acc[0][q]+bd.x, acc[1][q]+bd.y,
                               acc[2][q]+bd.z, acc[3][q]+bd.w);
        size_t o = (size_t)k * IDIM + d;
        *(float4*)&out[o]        = v;                       // samples
        *(float4*)&out[o + SO]   = v;                       // means
        *(float4*)&out[o + 2*SO] = make_float4(0.f,0.f,0.f,0.f); // sigmas
      }
    }
  }
}

extern "C" void kernel_launch(void* const* d_in, const int* in_sizes, int n_in,
                              void* d_out, int out_size, void* d_ws, size_t ws_size,
                              hipStream_t stream) {
  const float* x0    = (const float*)d_in[0];
  const float* W_enc = (const float*)d_in[1];
  const float* b_enc = (const float*)d_in[2];
  const float* W_ih  = (const float*)d_in[3];
  const float* W_hh  = (const float*)d_in[4];
  const float* b_ih  = (const float*)d_in[5];
  const float* b_n   = (const float*)d_in[6];
  const float* W_dec = (const float*)d_in[7];
  const float* b_dec = (const float*)d_in[8];
  (void)in_sizes; (void)n_in; (void)out_size; (void)ws_size;

  float* out = (float*)d_out;
  float* ws  = (float*)d_ws;
  float* M   = ws + WS_M;
  float* P   = ws + WS_P;
  float* q   = ws + WS_Q;
  float* ig1 = ws + WS_IG1;
  float* H_T = ws + WS_HT;
  float* scratch = out;   // 500*16384 floats = 32 MB of d_out, dead until k_decode

  hipLaunchKernelGGL(k_enc,     dim3(256),    dim3(256), 0, stream, W_enc, x0, b_dec, ws);
  hipLaunchKernelGGL(k_gemmM,   dim3(500),    dim3(256), 0, stream, W_enc, W_dec, scratch);
  hipLaunchKernelGGL(k_reduceM, dim3(64),     dim3(256), 0, stream, scratch, M);
  hipLaunchKernelGGL(k_smallP,  dim3(384),    dim3(128), 0, stream, W_ih, b_ih, b_enc, ws, M, P, q, ig1);
  hipLaunchKernelGGL(k_recur,   dim3(1),      dim3(768), 0, stream, P, W_hh, q, b_n, ig1, H_T);
  hipLaunchKernelGGL(k_decode,  dim3(782, 2), dim3(256), 0, stream, W_dec, b_dec, H_T, out);
}

// Round 3
// 440.652 us; speedup vs baseline: 1.1318x; 1.1318x over previous
//
#include <hip/hip_runtime.h>
#include <math.h>

#define HIDDEN 128
#define IDIM   50000
#define STEPS  100

// ws layout (float offsets)
#define WS_E1H  0        // 256   e1 partials [2][128]
#define WS_CH   256      // 256   c  partials [2][128]
#define WS_M    512      // 16384 M = W_enc@W_dec (128x128)
#define WS_P    16896    // 49152 P = W_ih@M (384x128)
#define WS_Q    66048    // 384   q = W_ih@(c+b_enc)+b_ih
#define WS_IG1  66432    // 384   ig1 = W_ih@(e1+b_enc)+b_ih
#define WS_HT   66816    // 16384 H_T[i][k] (128x128, cols 0..99 used)

// d_out scratch layout (float offsets). All dead before k_decode writes.
#define SC_PART 0        // 500*16384 = 8.19M floats: M partials
#define SC_MP   9000000  // 10*16384 floats: stage-1 reduced partials

__device__ __forceinline__ float sigmoidf_(float x){ return 1.0f/(1.0f+expf(-x)); }

// e1p[half][r] = dot(W_enc[r, half*25000 : +25000], x0); cp likewise vs b_dec.
__global__ __launch_bounds__(256) void k_enc(const float* __restrict__ W_enc,
    const float* __restrict__ x0, const float* __restrict__ b_dec,
    float* __restrict__ ws)
{
  const int r    = blockIdx.x >> 1;
  const int half = blockIdx.x & 1;
  const float4* wr = (const float4*)(W_enc + (size_t)r*IDIM + half*25000);
  const float4* xv = (const float4*)(x0   + half*25000);
  const float4* bv = (const float4*)(b_dec + half*25000);
  float s0 = 0.f, s1 = 0.f;
  for (int i = threadIdx.x; i < 6250; i += 256){
    float4 w = wr[i]; float4 a = xv[i]; float4 b = bv[i];
    s0 += w.x*a.x + w.y*a.y + w.z*a.z + w.w*a.w;
    s1 += w.x*b.x + w.y*b.y + w.z*b.z + w.w*b.w;
  }
  __shared__ float r0[256], r1[256];
  r0[threadIdx.x] = s0; r1[threadIdx.x] = s1;
  __syncthreads();
  for (int off = 128; off > 0; off >>= 1){
    if (threadIdx.x < off){
      r0[threadIdx.x] += r0[threadIdx.x+off];
      r1[threadIdx.x] += r1[threadIdx.x+off];
    }
    __syncthreads();
  }
  if (threadIdx.x == 0){
    ws[WS_E1H + half*128 + r] = r0[0];
    ws[WS_CH  + half*128 + r] = r1[0];
  }
}

// M partials: 500 blocks, K-chunk of 100 each; 128x128 tile, 8x8 micro-tile.
// __launch_bounds__(256,2): cap 256 VGPRs so acc[8][8] (64 regs) + temps
// stays resident. Bare (256) let the allocator target high occupancy and
// (likely) spill the accumulator in R1/R2.
__global__ __launch_bounds__(256, 2) void k_gemmM(const float* __restrict__ W_enc,
    const float* __restrict__ W_dec, float* __restrict__ scratch)
{
  __shared__ __align__(16) float As[4][128];
  __shared__ __align__(16) float Bs[4][128];
  const int t  = threadIdx.x;
  const int tx = t & 15, ty = t >> 4;
  const int d0 = blockIdx.x * 100;
  float acc[8][8];
  #pragma unroll
  for (int p = 0; p < 8; p++)
    #pragma unroll
    for (int q = 0; q < 8; q++) acc[p][q] = 0.f;

  for (int k0 = 0; k0 < 100; k0 += 4){
    __syncthreads();
    if (t < 128){
      float4 w = *(const float4*)(W_enc + (size_t)t*IDIM + d0 + k0);
      As[0][t] = w.x; As[1][t] = w.y; As[2][t] = w.z; As[3][t] = w.w;
    } else {
      int u = t - 128; int kk = u >> 5, g = u & 31;
      *(float4*)&Bs[kk][g*4] = *(const float4*)(W_dec + (size_t)(d0+k0+kk)*HIDDEN + g*4);
    }
    __syncthreads();
    #pragma unroll
    for (int kk = 0; kk < 4; kk++){
      float4 alo = *(const float4*)&As[kk][ty*8];
      float4 ahi = *(const float4*)&As[kk][ty*8+4];
      float4 blo = *(const float4*)&Bs[kk][tx*8];
      float4 bhi = *(const float4*)&Bs[kk][tx*8+4];
      float a[8] = {alo.x,alo.y,alo.z,alo.w,ahi.x,ahi.y,ahi.z,ahi.w};
      float b[8] = {blo.x,blo.y,blo.z,blo.w,bhi.x,bhi.y,bhi.z,bhi.w};
      #pragma unroll
      for (int p = 0; p < 8; p++)
        #pragma unroll
        for (int q = 0; q < 8; q++) acc[p][q] += a[p]*b[q];
    }
  }
  float* outp = scratch + (size_t)blockIdx.x * 16384;
  #pragma unroll
  for (int p = 0; p < 8; p++){
    #pragma unroll
    for (int q = 0; q < 8; q += 4){
      *(float4*)&outp[(ty*8+p)*128 + tx*8 + q] =
        make_float4(acc[p][q], acc[p][q+1], acc[p][q+2], acc[p][q+3]);
    }
  }
}

// Stage 1: 640 blocks; block (chunk, g) sums partials g*50..g*50+49 for its
// 256-element idx chunk. 2.5 blocks/CU, 50-deep -> latency well hidden
// (R2's single 64-block 500-deep walk was latency-bound).
__global__ __launch_bounds__(256) void k_reduce1(const float* __restrict__ scratch,
    float* __restrict__ Mp)
{
  const int g     = blockIdx.x % 10;
  const int chunk = blockIdx.x / 10;
  const int idx   = chunk * 256 + threadIdx.x;
  const float* base = scratch + (size_t)(g*50) * 16384 + idx;
  float s[10];
  #pragma unroll
  for (int u = 0; u < 10; u++) s[u] = 0.f;
  for (int p = 0; p < 50; p += 10){
    #pragma unroll
    for (int u = 0; u < 10; u++)
      s[u] += base[(size_t)(p+u)*16384];
  }
  float t0 = (s[0]+s[1]) + (s[2]+s[3]);
  float t1 = (s[4]+s[5]) + (s[6]+s[7]);
  Mp[(size_t)g*16384 + idx] = t0 + t1 + (s[8]+s[9]);
}

// Stage 2: 64 blocks, sum 10 -> M.
__global__ __launch_bounds__(256) void k_reduce2(const float* __restrict__ Mp,
    float* __restrict__ Mout)
{
  const int idx = blockIdx.x * 256 + threadIdx.x;
  float s = 0.f;
  #pragma unroll
  for (int g = 0; g < 10; g++) s += Mp[(size_t)g*16384 + idx];
  Mout[idx] = s;
}

// P[r,:] = W_ih[r,:]@M ; q[r] ; ig1[r]. 384 blocks x 128 threads.
__global__ __launch_bounds__(128) void k_smallP(const float* __restrict__ W_ih,
    const float* __restrict__ b_ih, const float* __restrict__ b_enc,
    const float* __restrict__ ws, const float* __restrict__ M,
    float* __restrict__ P, float* __restrict__ q, float* __restrict__ ig1)
{
  const int r = blockIdx.x, j = threadIdx.x;
  const float* wr = W_ih + (size_t)r * HIDDEN;
  float acc = 0.f;
  for (int k = 0; k < HIDDEN; k++) acc += wr[k] * M[k*HIDDEN + j];
  P[(size_t)r*HIDDEN + j] = acc;
  const float wj = wr[j];
  float cj  = ws[WS_CH  + j] + ws[WS_CH  + 128 + j];
  float e1j = ws[WS_E1H + j] + ws[WS_E1H + 128 + j];
  float t0 = wj * (cj  + b_enc[j]);
  float t1 = wj * (e1j + b_enc[j]);
  __shared__ float r0[128], r1[128];
  r0[j] = t0; r1[j] = t1;
  __syncthreads();
  for (int off = 64; off > 0; off >>= 1){
    if (j < off){ r0[j] += r0[j+off]; r1[j] += r1[j+off]; }
    __syncthreads();
  }
  if (j == 0){
    q[r]   = r0[0] + b_ih[r];
    ig1[r] = r1[0] + b_ih[r];
  }
}

// Sequential recurrence: 1 block, 768 threads, thread t owns row t of [P;W_hh]
// in 128 VGPRs. amdgpu_waves_per_eu(3,3) FORCES the register budget to
// 512/3 = 170 (launch_bounds' 2nd arg is only a MIN — R2 proved LLVM still
// targeted 6 waves/EU and spilled all 128 weight regs at VGPR_Count=84).
__global__ __launch_bounds__(768)
__attribute__((amdgpu_waves_per_eu(3, 3)))
void k_recur(const float* __restrict__ P,
    const float* __restrict__ W_hh, const float* __restrict__ q,
    const float* __restrict__ b_n, const float* __restrict__ ig1,
    float* __restrict__ H_T)
{
  const int t = threadIdx.x;
  float4 wv[32];
  float qq;
  if (t < 384){
    const float4* src = (const float4*)(P + (size_t)t * HIDDEN);
    #pragma unroll
    for (int j = 0; j < 32; j++) wv[j] = src[j];
    qq = q[t];
  } else {
    const float4* src = (const float4*)(W_hh + (size_t)(t-384) * HIDDEN);
    #pragma unroll
    for (int j = 0; j < 32; j++) wv[j] = src[j];
    qq = 0.f;
  }
  __shared__ __align__(16) float h[HIDDEN];
  __shared__ float z[768];
  __shared__ float bn[HIDDEN];
  if (t < HIDDEN){
    float bnv   = b_n[t];
    float reset = sigmoidf_(ig1[t]);
    float inp   = sigmoidf_(ig1[128+t]);
    float nw    = tanhf(ig1[256+t] + reset * bnv);
    float h1    = nw + inp * (0.f - nw);
    bn[t] = bnv;
    h[t]  = h1;
    H_T[(size_t)t*HIDDEN] = h1;
  }
  __syncthreads();
  for (int k = 1; k < STEPS; k++){
    float a0 = qq, a1 = 0.f, a2 = 0.f, a3 = 0.f;
    const float4* h4 = (const float4*)h;
    #pragma unroll
    for (int j = 0; j < 32; j += 4){
      float4 h0 = h4[j+0];
      a0 += wv[j+0].x*h0.x + wv[j+0].y*h0.y + wv[j+0].z*h0.z + wv[j+0].w*h0.w;
      float4 h1v = h4[j+1];
      a1 += wv[j+1].x*h1v.x + wv[j+1].y*h1v.y + wv[j+1].z*h1v.z + wv[j+1].w*h1v.w;
      float4 h2 = h4[j+2];
      a2 += wv[j+2].x*h2.x + wv[j+2].y*h2.y + wv[j+2].z*h2.z + wv[j+2].w*h2.w;
      float4 h3 = h4[j+3];
      a3 += wv[j+3].x*h3.x + wv[j+3].y*h3.y + wv[j+3].z*h3.z + wv[j+3].w*h3.w;
    }
    z[t] = (a0+a1) + (a2+a3);
    __syncthreads();
    if (t < HIDDEN){
      float reset = sigmoidf_(z[t]       + z[384+t]);
      float inp   = sigmoidf_(z[128+t]   + z[512+t]);
      float nw    = tanhf(z[256+t] + reset*(z[640+t] + bn[t]));
      float hn    = nw + inp*(h[t] - nw);
      H_T[(size_t)t*HIDDEN + k] = hn;
      h[t] = hn;        // other threads read h only after the barrier below
    }
    __syncthreads();
  }
}

// X[k][d] = W_dec[d,:]@h_k + b_dec[d]. One k-tile of 128 covers all 100 steps:
// W_dec read ONCE (was twice), 16x-redundant L1 A-loads halved. Micro 4d x 8k.
// __launch_bounds__(256,4): cap 128 VGPRs (need ~90: acc 32 + a 16 + b 8 + addr).
__global__ __launch_bounds__(256, 4) void k_decode(const float* __restrict__ W_dec,
    const float* __restrict__ b_dec, const float* __restrict__ H_T,
    float* __restrict__ out)
{
  __shared__ __align__(16) float Bs[128][132];
  const int t  = threadIdx.x;
  const int tx = t & 15, ty = t >> 4;
  const int d0 = blockIdx.x * 64;

  // stage all of H_T (128x128) -> Bs
  for (int l = t; l < 4096; l += 256){
    int j = l >> 5, g = l & 31;
    *(float4*)&Bs[j][g*4] = *(const float4*)&H_T[(size_t)j*HIDDEN + g*4];
  }
  __syncthreads();

  const int d  = d0 + tx*4;               // multiple of 4
  const int dc = (d < IDIM) ? d : 0;      // clamp: garbage rows never stored
  const float* A0 = W_dec + (size_t)dc * HIDDEN;
  const float* A1 = A0 + HIDDEN;
  const float* A2 = A1 + HIDDEN;
  const float* A3 = A2 + HIDDEN;

  float acc[4][8];
  #pragma unroll
  for (int p = 0; p < 4; p++)
    #pragma unroll
    for (int q = 0; q < 8; q++) acc[p][q] = 0.f;

  for (int j0 = 0; j0 < HIDDEN; j0 += 4){
    float4 a0 = *(const float4*)(A0 + j0);
    float4 a1 = *(const float4*)(A1 + j0);
    float4 a2 = *(const float4*)(A2 + j0);
    float4 a3 = *(const float4*)(A3 + j0);
    #pragma unroll
    for (int jj = 0; jj < 4; jj++){
      float4 b0 = *(const float4*)&Bs[j0+jj][ty*8];
      float4 b1 = *(const float4*)&Bs[j0+jj][ty*8+4];
      float e0 = (jj==0)?a0.x:(jj==1)?a0.y:(jj==2)?a0.z:a0.w;
      float e1 = (jj==0)?a1.x:(jj==1)?a1.y:(jj==2)?a1.z:a1.w;
      float e2 = (jj==0)?a2.x:(jj==1)?a2.y:(jj==2)?a2.z:a2.w;
      float e3 = (jj==0)?a3.x:(jj==1)?a3.y:(jj==2)?a3.z:a3.w;
      acc[0][0]+=e0*b0.x; acc[0][1]+=e0*b0.y; acc[0][2]+=e0*b0.z; acc[0][3]+=e0*b0.w;
      acc[0][4]+=e0*b1.x; acc[0][5]+=e0*b1.y; acc[0][6]+=e0*b1.z; acc[0][7]+=e0*b1.w;
      acc[1][0]+=e1*b0.x; acc[1][1]+=e1*b0.y; acc[1][2]+=e1*b0.z; acc[1][3]+=e1*b0.w;
      acc[1][4]+=e1*b1.x; acc[1][5]+=e1*b1.y; acc[1][6]+=e1*b1.z; acc[1][7]+=e1*b1.w;
      acc[2][0]+=e2*b0.x; acc[2][1]+=e2*b0.y; acc[2][2]+=e2*b0.z; acc[2][3]+=e2*b0.w;
      acc[2][4]+=e2*b1.x; acc[2][5]+=e2*b1.y; acc[2][6]+=e2*b1.z; acc[2][7]+=e2*b1.w;
      acc[3][0]+=e3*b0.x; acc[3][1]+=e3*b0.y; acc[3][2]+=e3*b0.z; acc[3][3]+=e3*b0.w;
      acc[3][4]+=e3*b1.x; acc[3][5]+=e3*b1.y; acc[3][6]+=e3*b1.z; acc[3][7]+=e3*b1.w;
    }
  }

  if (d < IDIM){
    float4 bd = *(const float4*)&b_dec[d];
    const size_t SO = (size_t)STEPS * IDIM;  // 5,000,000
    #pragma unroll
    for (int qq = 0; qq < 8; qq++){
      int k = ty*8 + qq;
      if (k < STEPS){
        float4 v = make_float4(acc[0][qq]+bd.x, acc[1][qq]+bd.y,
                               acc[2][qq]+bd.z, acc[3][qq]+bd.w);
        size_t o = (size_t)k * IDIM + d;
        *(float4*)&out[o]        = v;                       // samples
        *(float4*)&out[o + SO]   = v;                       // means
        *(float4*)&out[o + 2*SO] = make_float4(0.f,0.f,0.f,0.f); // sigmas
      }
    }
  }
}

extern "C" void kernel_launch(void* const* d_in, const int* in_sizes, int n_in,
                              void* d_out, int out_size, void* d_ws, size_t ws_size,
                              hipStream_t stream) {
  const float* x0    = (const float*)d_in[0];
  const float* W_enc = (const float*)d_in[1];
  const float* b_enc = (const float*)d_in[2];
  const float* W_ih  = (const float*)d_in[3];
  const float* W_hh  = (const float*)d_in[4];
  const float* b_ih  = (const float*)d_in[5];
  const float* b_n   = (const float*)d_in[6];
  const float* W_dec = (const float*)d_in[7];
  const float* b_dec = (const float*)d_in[8];
  (void)in_sizes; (void)n_in; (void)out_size; (void)ws_size;

  float* out = (float*)d_out;
  float* ws  = (float*)d_ws;
  float* M   = ws + WS_M;
  float* P   = ws + WS_P;
  float* q   = ws + WS_Q;
  float* ig1 = ws + WS_IG1;
  float* H_T = ws + WS_HT;
  float* scratch = out + SC_PART;  // 32 MB of d_out, dead until k_decode
  float* Mp      = out + SC_MP;    // 640 KB of d_out, ditto

  hipLaunchKernelGGL(k_enc,     dim3(256), dim3(256), 0, stream, W_enc, x0, b_dec, ws);
  hipLaunchKernelGGL(k_gemmM,   dim3(500), dim3(256), 0, stream, W_enc, W_dec, scratch);
  hipLaunchKernelGGL(k_reduce1, dim3(640), dim3(256), 0, stream, scratch, Mp);
  hipLaunchKernelGGL(k_reduce2, dim3(64),  dim3(256), 0, stream, Mp, M);
  hipLaunchKernelGGL(k_smallP,  dim3(384), dim3(128), 0, stream, W_ih, b_ih, b_enc, ws, M, P, q, ig1);
  hipLaunchKernelGGL(k_recur,   dim3(1),   dim3(768), 0, stream, P, W_hh, q, b_n, ig1, H_T);
  hipLaunchKernelGGL(k_decode,  dim3(782), dim3(256), 0, stream, W_dec, b_dec, H_T, out);
}

// Round 4
// 339.299 us; speedup vs baseline: 1.4699x; 1.2987x over previous
//
#include <hip/hip_runtime.h>
#include <math.h>

#define HIDDEN 128
#define IDIM   50000
#define STEPS  100

typedef _Float16 half_t;
typedef _Float16 h2_t __attribute__((ext_vector_type(2)));

// ws layout (float offsets)
#define WS_E1H  0        // 256   e1 partials [2][128]
#define WS_CH   256      // 256   c  partials [2][128]
#define WS_M    512      // 16384 M = W_enc@W_dec (128x128)
#define WS_P    16896    // 49152 P = W_ih@M (384x128)
#define WS_Q    66048    // 384   q = W_ih@(c+b_enc)+b_ih
#define WS_IG1  66432    // 384   ig1 = W_ih@(e1+b_enc)+b_ih
#define WS_HT   66816    // 16384 H_T[i][k] (128x128, cols 0..99 used)

// d_out scratch layout (float offsets). All dead before k_decode writes.
#define SC_PART 0        // 500*16384 = 8.19M floats: M partials
#define SC_MP   9000000  // 10*16384 floats: stage-1 reduced partials

__device__ __forceinline__ float sigmoidf_(float x){ return 1.0f/(1.0f+expf(-x)); }

// e1p[half][r] = dot(W_enc[r, half*25000 : +25000], x0); cp likewise vs b_dec.
__global__ __launch_bounds__(256) void k_enc(const float* __restrict__ W_enc,
    const float* __restrict__ x0, const float* __restrict__ b_dec,
    float* __restrict__ ws)
{
  const int r    = blockIdx.x >> 1;
  const int half = blockIdx.x & 1;
  const float4* wr = (const float4*)(W_enc + (size_t)r*IDIM + half*25000);
  const float4* xv = (const float4*)(x0   + half*25000);
  const float4* bv = (const float4*)(b_dec + half*25000);
  float s0 = 0.f, s1 = 0.f;
  for (int i = threadIdx.x; i < 6250; i += 256){
    float4 w = wr[i]; float4 a = xv[i]; float4 b = bv[i];
    s0 += w.x*a.x + w.y*a.y + w.z*a.z + w.w*a.w;
    s1 += w.x*b.x + w.y*b.y + w.z*b.z + w.w*b.w;
  }
  __shared__ float r0[256], r1[256];
  r0[threadIdx.x] = s0; r1[threadIdx.x] = s1;
  __syncthreads();
  for (int off = 128; off > 0; off >>= 1){
    if (threadIdx.x < off){
      r0[threadIdx.x] += r0[threadIdx.x+off];
      r1[threadIdx.x] += r1[threadIdx.x+off];
    }
    __syncthreads();
  }
  if (threadIdx.x == 0){
    ws[WS_E1H + half*128 + r] = r0[0];
    ws[WS_CH  + half*128 + r] = r1[0];
  }
}

// M partials: 500 blocks, K-chunk of 100 each; 128x128 tile, 8x8 micro-tile.
// Register prefetch pipeline: next chunk's global loads issue before compute,
// so their ~200-900 cyc latency hides under the 4x64-FMA inner block (R3's
// load->barrier->compute structure exposed the full latency every 4-k iter).
__global__ __launch_bounds__(256, 2) void k_gemmM(const float* __restrict__ W_enc,
    const float* __restrict__ W_dec, float* __restrict__ scratch)
{
  __shared__ __align__(16) float As[4][128];
  __shared__ __align__(16) float Bs[4][128];
  const int t  = threadIdx.x;
  const int tx = t & 15, ty = t >> 4;
  const int d0 = blockIdx.x * 100;
  const int u  = t - 128, ukk = u >> 5, ug = u & 31;   // B-loader coords
  float acc[8][8];
  #pragma unroll
  for (int p = 0; p < 8; p++)
    #pragma unroll
    for (int q = 0; q < 8; q++) acc[p][q] = 0.f;

  float4 stage;
  if (t < 128) stage = *(const float4*)(W_enc + (size_t)t*IDIM + d0);
  else         stage = *(const float4*)(W_dec + (size_t)(d0+ukk)*HIDDEN + ug*4);

  for (int k0 = 0; k0 < 100; k0 += 4){
    if (t < 128){
      As[0][t] = stage.x; As[1][t] = stage.y; As[2][t] = stage.z; As[3][t] = stage.w;
    } else {
      *(float4*)&Bs[ukk][ug*4] = stage;
    }
    __syncthreads();
    if (k0 + 4 < 100){   // prefetch next chunk while LDS tile is consumed
      if (t < 128) stage = *(const float4*)(W_enc + (size_t)t*IDIM + d0 + k0 + 4);
      else         stage = *(const float4*)(W_dec + (size_t)(d0+k0+4+ukk)*HIDDEN + ug*4);
    }
    #pragma unroll
    for (int kk = 0; kk < 4; kk++){
      float4 alo = *(const float4*)&As[kk][ty*8];
      float4 ahi = *(const float4*)&As[kk][ty*8+4];
      float4 blo = *(const float4*)&Bs[kk][tx*8];
      float4 bhi = *(const float4*)&Bs[kk][tx*8+4];
      float a[8] = {alo.x,alo.y,alo.z,alo.w,ahi.x,ahi.y,ahi.z,ahi.w};
      float b[8] = {blo.x,blo.y,blo.z,blo.w,bhi.x,bhi.y,bhi.z,bhi.w};
      #pragma unroll
      for (int p = 0; p < 8; p++)
        #pragma unroll
        for (int q = 0; q < 8; q++) acc[p][q] += a[p]*b[q];
    }
    __syncthreads();
  }
  float* outp = scratch + (size_t)blockIdx.x * 16384;
  #pragma unroll
  for (int p = 0; p < 8; p++){
    #pragma unroll
    for (int q = 0; q < 8; q += 4){
      *(float4*)&outp[(ty*8+p)*128 + tx*8 + q] =
        make_float4(acc[p][q], acc[p][q+1], acc[p][q+2], acc[p][q+3]);
    }
  }
}

// Stage 1: 640 blocks; block (chunk, g) sums partials g*50..g*50+49.
__global__ __launch_bounds__(256) void k_reduce1(const float* __restrict__ scratch,
    float* __restrict__ Mp)
{
  const int g     = blockIdx.x % 10;
  const int chunk = blockIdx.x / 10;
  const int idx   = chunk * 256 + threadIdx.x;
  const float* base = scratch + (size_t)(g*50) * 16384 + idx;
  float s[10];
  #pragma unroll
  for (int uu = 0; uu < 10; uu++) s[uu] = 0.f;
  for (int p = 0; p < 50; p += 10){
    #pragma unroll
    for (int uu = 0; uu < 10; uu++)
      s[uu] += base[(size_t)(p+uu)*16384];
  }
  float t0 = (s[0]+s[1]) + (s[2]+s[3]);
  float t1 = (s[4]+s[5]) + (s[6]+s[7]);
  Mp[(size_t)g*16384 + idx] = t0 + t1 + (s[8]+s[9]);
}

// Stage 2: 64 blocks, sum 10 -> M.
__global__ __launch_bounds__(256) void k_reduce2(const float* __restrict__ Mp,
    float* __restrict__ Mout)
{
  const int idx = blockIdx.x * 256 + threadIdx.x;
  float s = 0.f;
  #pragma unroll
  for (int g = 0; g < 10; g++) s += Mp[(size_t)g*16384 + idx];
  Mout[idx] = s;
}

// P[r,:] = W_ih[r,:]@M ; q[r] ; ig1[r]. 384 blocks x 128 threads.
__global__ __launch_bounds__(128) void k_smallP(const float* __restrict__ W_ih,
    const float* __restrict__ b_ih, const float* __restrict__ b_enc,
    const float* __restrict__ ws, const float* __restrict__ M,
    float* __restrict__ P, float* __restrict__ q, float* __restrict__ ig1)
{
  const int r = blockIdx.x, j = threadIdx.x;
  const float* wr = W_ih + (size_t)r * HIDDEN;
  float acc = 0.f;
  #pragma unroll 8
  for (int k = 0; k < HIDDEN; k++) acc += wr[k] * M[k*HIDDEN + j];
  P[(size_t)r*HIDDEN + j] = acc;
  const float wj = wr[j];
  float cj  = ws[WS_CH  + j] + ws[WS_CH  + 128 + j];
  float e1j = ws[WS_E1H + j] + ws[WS_E1H + 128 + j];
  float t0 = wj * (cj  + b_enc[j]);
  float t1 = wj * (e1j + b_enc[j]);
  __shared__ float r0[128], r1[128];
  r0[j] = t0; r1[j] = t1;
  __syncthreads();
  for (int off = 64; off > 0; off >>= 1){
    if (j < off){ r0[j] += r0[j+off]; r1[j] += r1[j+off]; }
    __syncthreads();
  }
  if (j == 0){
    q[r]   = r0[0] + b_ih[r];
    ig1[r] = r1[0] + b_ih[r];
  }
}

// Sequential recurrence, f16 edition. Thread t owns row t of [P;W_hh] as
// 64 packed f16x2 VGPRs (64 regs — fits UNDER the ~85-reg budget the
// allocator enforced in R2/R3, so no spill regardless of heuristics).
// Matvec via v_dot2_f32_f16 (f16 mul, fp32 accumulate); h broadcast from LDS
// as f16 (16 ds_read_b128/thread/step — half of R3's 32). Gates, h-update,
// and H_T output all stay fp32.
__global__
__attribute__((amdgpu_flat_work_group_size(768, 768), amdgpu_waves_per_eu(3, 4)))
void k_recur(const float* __restrict__ P,
    const float* __restrict__ W_hh, const float* __restrict__ q,
    const float* __restrict__ b_n, const float* __restrict__ ig1,
    float* __restrict__ H_T)
{
  const int t = threadIdx.x;
  const float* src = (t < 384) ? (P + (size_t)t * HIDDEN)
                               : (W_hh + (size_t)(t - 384) * HIDDEN);
  float qq = (t < 384) ? q[t] : 0.f;

  h2_t w2[64];
  const float4* src4 = (const float4*)src;
  #pragma unroll
  for (int j = 0; j < 32; j++){
    float4 wf = src4[j];
    h2_t p0; p0.x = (half_t)wf.x; p0.y = (half_t)wf.y;
    h2_t p1; p1.x = (half_t)wf.z; p1.y = (half_t)wf.w;
    w2[2*j]   = p0;
    w2[2*j+1] = p1;
  }

  __shared__ float h32[HIDDEN];
  __shared__ __align__(16) half_t h16[HIDDEN];
  __shared__ float z[768];
  __shared__ float bn[HIDDEN];
  if (t < HIDDEN){
    float bnv   = b_n[t];
    float reset = sigmoidf_(ig1[t]);
    float inp   = sigmoidf_(ig1[128+t]);
    float nw    = tanhf(ig1[256+t] + reset * bnv);
    float h1    = nw + inp * (0.f - nw);
    bn[t]  = bnv;
    h32[t] = h1;
    h16[t] = (half_t)h1;
    H_T[(size_t)t*HIDDEN] = h1;
  }
  __syncthreads();

  const uint4* hq = (const uint4*)h16;   // 16 x uint4 = 128 f16
  for (int k = 1; k < STEPS; k++){
    float a0 = qq, a1 = 0.f, a2 = 0.f, a3 = 0.f;
    #pragma unroll
    for (int jj = 0; jj < 16; jj++){
      uint4 hb = hq[jj];
      h2_t hp0 = __builtin_bit_cast(h2_t, hb.x);
      h2_t hp1 = __builtin_bit_cast(h2_t, hb.y);
      h2_t hp2 = __builtin_bit_cast(h2_t, hb.z);
      h2_t hp3 = __builtin_bit_cast(h2_t, hb.w);
      a0 = __builtin_amdgcn_fdot2(w2[4*jj+0], hp0, a0, false);
      a1 = __builtin_amdgcn_fdot2(w2[4*jj+1], hp1, a1, false);
      a2 = __builtin_amdgcn_fdot2(w2[4*jj+2], hp2, a2, false);
      a3 = __builtin_amdgcn_fdot2(w2[4*jj+3], hp3, a3, false);
    }
    z[t] = (a0+a1) + (a2+a3);
    __syncthreads();
    if (t < HIDDEN){
      float reset = sigmoidf_(z[t]       + z[384+t]);
      float inp   = sigmoidf_(z[128+t]   + z[512+t]);
      float nw    = tanhf(z[256+t] + reset*(z[640+t] + bn[t]));
      float hn    = nw + inp*(h32[t] - nw);
      H_T[(size_t)t*HIDDEN + k] = hn;
      h32[t] = hn;
      h16[t] = (half_t)hn;   // consumers read only after the barrier below
    }
    __syncthreads();
  }
}

// X[k][d] = W_dec[d,:]@h_k + b_dec[d]. One k-tile of 128 covers all 100 steps.
__global__ __launch_bounds__(256, 4) void k_decode(const float* __restrict__ W_dec,
    const float* __restrict__ b_dec, const float* __restrict__ H_T,
    float* __restrict__ out)
{
  __shared__ __align__(16) float Bs[128][132];
  const int t  = threadIdx.x;
  const int tx = t & 15, ty = t >> 4;
  const int d0 = blockIdx.x * 64;

  for (int l = t; l < 4096; l += 256){
    int j = l >> 5, g = l & 31;
    *(float4*)&Bs[j][g*4] = *(const float4*)&H_T[(size_t)j*HIDDEN + g*4];
  }
  __syncthreads();

  const int d  = d0 + tx*4;
  const int dc = (d < IDIM) ? d : 0;
  const float* A0 = W_dec + (size_t)dc * HIDDEN;
  const float* A1 = A0 + HIDDEN;
  const float* A2 = A1 + HIDDEN;
  const float* A3 = A2 + HIDDEN;

  float acc[4][8];
  #pragma unroll
  for (int p = 0; p < 4; p++)
    #pragma unroll
    for (int q = 0; q < 8; q++) acc[p][q] = 0.f;

  for (int j0 = 0; j0 < HIDDEN; j0 += 4){
    float4 a0 = *(const float4*)(A0 + j0);
    float4 a1 = *(const float4*)(A1 + j0);
    float4 a2 = *(const float4*)(A2 + j0);
    float4 a3 = *(const float4*)(A3 + j0);
    #pragma unroll
    for (int jj = 0; jj < 4; jj++){
      float4 b0 = *(const float4*)&Bs[j0+jj][ty*8];
      float4 b1 = *(const float4*)&Bs[j0+jj][ty*8+4];
      float e0 = (jj==0)?a0.x:(jj==1)?a0.y:(jj==2)?a0.z:a0.w;
      float e1 = (jj==0)?a1.x:(jj==1)?a1.y:(jj==2)?a1.z:a1.w;
      float e2 = (jj==0)?a2.x:(jj==1)?a2.y:(jj==2)?a2.z:a2.w;
      float e3 = (jj==0)?a3.x:(jj==1)?a3.y:(jj==2)?a3.z:a3.w;
      acc[0][0]+=e0*b0.x; acc[0][1]+=e0*b0.y; acc[0][2]+=e0*b0.z; acc[0][3]+=e0*b0.w;
      acc[0][4]+=e0*b1.x; acc[0][5]+=e0*b1.y; acc[0][6]+=e0*b1.z; acc[0][7]+=e0*b1.w;
      acc[1][0]+=e1*b0.x; acc[1][1]+=e1*b0.y; acc[1][2]+=e1*b0.z; acc[1][3]+=e1*b0.w;
      acc[1][4]+=e1*b1.x; acc[1][5]+=e1*b1.y; acc[1][6]+=e1*b1.z; acc[1][7]+=e1*b1.w;
      acc[2][0]+=e2*b0.x; acc[2][1]+=e2*b0.y; acc[2][2]+=e2*b0.z; acc[2][3]+=e2*b0.w;
      acc[2][4]+=e2*b1.x; acc[2][5]+=e2*b1.y; acc[2][6]+=e2*b1.z; acc[2][7]+=e2*b1.w;
      acc[3][0]+=e3*b0.x; acc[3][1]+=e3*b0.y; acc[3][2]+=e3*b0.z; acc[3][3]+=e3*b0.w;
      acc[3][4]+=e3*b1.x; acc[3][5]+=e3*b1.y; acc[3][6]+=e3*b1.z; acc[3][7]+=e3*b1.w;
    }
  }

  if (d < IDIM){
    float4 bd = *(const float4*)&b_dec[d];
    const size_t SO = (size_t)STEPS * IDIM;  // 5,000,000
    #pragma unroll
    for (int qq = 0; qq < 8; qq++){
      int k = ty*8 + qq;
      if (k < STEPS){
        float4 v = make_float4(acc[0][qq]+bd.x, acc[1][qq]+bd.y,
                               acc[2][qq]+bd.z, acc[3][qq]+bd.w);
        size_t o = (size_t)k * IDIM + d;
        *(float4*)&out[o]        = v;                       // samples
        *(float4*)&out[o + SO]   = v;                       // means
        *(float4*)&out[o + 2*SO] = make_float4(0.f,0.f,0.f,0.f); // sigmas
      }
    }
  }
}

extern "C" void kernel_launch(void* const* d_in, const int* in_sizes, int n_in,
                              void* d_out, int out_size, void* d_ws, size_t ws_size,
                              hipStream_t stream) {
  const float* x0    = (const float*)d_in[0];
  const float* W_enc = (const float*)d_in[1];
  const float* b_enc = (const float*)d_in[2];
  const float* W_ih  = (const float*)d_in[3];
  const float* W_hh  = (const float*)d_in[4];
  const float* b_ih  = (const float*)d_in[5];
  const float* b_n   = (const float*)d_in[6];
  const float* W_dec = (const float*)d_in[7];
  const float* b_dec = (const float*)d_in[8];
  (void)in_sizes; (void)n_in; (void)out_size; (void)ws_size;

  float* out = (float*)d_out;
  float* ws  = (float*)d_ws;
  float* M   = ws + WS_M;
  float* P   = ws + WS_P;
  float* q   = ws + WS_Q;
  float* ig1 = ws + WS_IG1;
  float* H_T = ws + WS_HT;
  float* scratch = out + SC_PART;  // 32 MB of d_out, dead until k_decode
  float* Mp      = out + SC_MP;    // 640 KB of d_out, ditto

  hipLaunchKernelGGL(k_enc,     dim3(256), dim3(256), 0, stream, W_enc, x0, b_dec, ws);
  hipLaunchKernelGGL(k_gemmM,   dim3(500), dim3(256), 0, stream, W_enc, W_dec, scratch);
  hipLaunchKernelGGL(k_reduce1, dim3(640), dim3(256), 0, stream, scratch, Mp);
  hipLaunchKernelGGL(k_reduce2, dim3(64),  dim3(256), 0, stream, Mp, M);
  hipLaunchKernelGGL(k_smallP,  dim3(384), dim3(128), 0, stream, W_ih, b_ih, b_enc, ws, M, P, q, ig1);
  hipLaunchKernelGGL(k_recur,   dim3(1),   dim3(768), 0, stream, P, W_hh, q, b_n, ig1, H_T);
  hipLaunchKernelGGL(k_decode,  dim3(782), dim3(256), 0, stream, W_dec, b_dec, H_T, out);
}

// Round 5
// 324.005 us; speedup vs baseline: 1.5393x; 1.0472x over previous
//
#include <hip/hip_runtime.h>
#include <math.h>

#define HIDDEN 128
#define IDIM   50000
#define STEPS  100

typedef _Float16 half_t;
typedef _Float16 h2_t __attribute__((ext_vector_type(2)));

// ws layout (float offsets)
#define WS_E1H  0        // 256   e1 partials [2][128]
#define WS_CH   256      // 256   c  partials [2][128]
#define WS_M    512      // 16384 M = W_enc@W_dec (128x128)
#define WS_P    16896    // 49152 P = W_ih@M (384x128)
#define WS_Q    66048    // 384   q = W_ih@(c+b_enc)+b_ih
#define WS_IG1  66432    // 384   ig1 = W_ih@(e1+b_enc)+b_ih
#define WS_HT   66816    // 16384 H_T[i][k] (128x128, cols 0..99 used)

// d_out scratch layout (float offsets). All dead before k_decode writes.
#define SC_PART 0        // 500*16384 = 8.19M floats: M partials
#define SC_MP   9000000  // 10*16384 floats: stage-1 reduced partials

__device__ __forceinline__ float sigmoidf_(float x){ return 1.0f/(1.0f+expf(-x)); }

// Fused: blocks 0..499 = M-partial GEMM; blocks 500..755 = encoder dots.
// One launch instead of two serialized ones (cuts a graph-node gap; the two
// workloads are independent and now overlap on the device).
__global__ __launch_bounds__(256, 2) void k_encgemm(const float* __restrict__ W_enc,
    const float* __restrict__ W_dec, const float* __restrict__ x0,
    const float* __restrict__ b_dec, float* __restrict__ ws,
    float* __restrict__ scratch)
{
  __shared__ __align__(16) float smem[1024];
  const int t = threadIdx.x;

  if (blockIdx.x < 500){
    // ---- M partials: K-chunk of 100; 128x128 tile, 8x8 micro-tile ----
    float (*As)[128] = (float(*)[128])smem;          // [4][128]
    float (*Bs)[128] = (float(*)[128])(smem + 512);  // [4][128]
    const int tx = t & 15, ty = t >> 4;
    const int d0 = blockIdx.x * 100;
    const int u  = t - 128, ukk = u >> 5, ug = u & 31;
    float acc[8][8];
    #pragma unroll
    for (int p = 0; p < 8; p++)
      #pragma unroll
      for (int q = 0; q < 8; q++) acc[p][q] = 0.f;

    float4 stage;
    if (t < 128) stage = *(const float4*)(W_enc + (size_t)t*IDIM + d0);
    else         stage = *(const float4*)(W_dec + (size_t)(d0+ukk)*HIDDEN + ug*4);

    for (int k0 = 0; k0 < 100; k0 += 4){
      if (t < 128){
        As[0][t] = stage.x; As[1][t] = stage.y; As[2][t] = stage.z; As[3][t] = stage.w;
      } else {
        *(float4*)&Bs[ukk][ug*4] = stage;
      }
      __syncthreads();
      if (k0 + 4 < 100){
        if (t < 128) stage = *(const float4*)(W_enc + (size_t)t*IDIM + d0 + k0 + 4);
        else         stage = *(const float4*)(W_dec + (size_t)(d0+k0+4+ukk)*HIDDEN + ug*4);
      }
      #pragma unroll
      for (int kk = 0; kk < 4; kk++){
        float4 alo = *(const float4*)&As[kk][ty*8];
        float4 ahi = *(const float4*)&As[kk][ty*8+4];
        float4 blo = *(const float4*)&Bs[kk][tx*8];
        float4 bhi = *(const float4*)&Bs[kk][tx*8+4];
        float a[8] = {alo.x,alo.y,alo.z,alo.w,ahi.x,ahi.y,ahi.z,ahi.w};
        float b[8] = {blo.x,blo.y,blo.z,blo.w,bhi.x,bhi.y,bhi.z,bhi.w};
        #pragma unroll
        for (int p = 0; p < 8; p++)
          #pragma unroll
          for (int q = 0; q < 8; q++) acc[p][q] += a[p]*b[q];
      }
      __syncthreads();
    }
    float* outp = scratch + (size_t)blockIdx.x * 16384;
    #pragma unroll
    for (int p = 0; p < 8; p++){
      #pragma unroll
      for (int q = 0; q < 8; q += 4){
        *(float4*)&outp[(ty*8+p)*128 + tx*8 + q] =
          make_float4(acc[p][q], acc[p][q+1], acc[p][q+2], acc[p][q+3]);
      }
    }
  } else {
    // ---- encoder: e1p/cp block partials ----
    const int bid  = blockIdx.x - 500;
    const int r    = bid >> 1;
    const int half = bid & 1;
    float* r0 = smem;         // [256]
    float* r1 = smem + 256;   // [256]
    const float4* wr = (const float4*)(W_enc + (size_t)r*IDIM + half*25000);
    const float4* xv = (const float4*)(x0   + half*25000);
    const float4* bv = (const float4*)(b_dec + half*25000);
    float s0 = 0.f, s1 = 0.f;
    for (int i = t; i < 6250; i += 256){
      float4 w = wr[i]; float4 a = xv[i]; float4 b = bv[i];
      s0 += w.x*a.x + w.y*a.y + w.z*a.z + w.w*a.w;
      s1 += w.x*b.x + w.y*b.y + w.z*b.z + w.w*b.w;
    }
    r0[t] = s0; r1[t] = s1;
    __syncthreads();
    for (int off = 128; off > 0; off >>= 1){
      if (t < off){ r0[t] += r0[t+off]; r1[t] += r1[t+off]; }
      __syncthreads();
    }
    if (t == 0){
      ws[WS_E1H + half*128 + r] = r0[0];
      ws[WS_CH  + half*128 + r] = r1[0];
    }
  }
}

// Stage 1: 640 blocks; block (chunk, g) sums partials g*50..g*50+49.
__global__ __launch_bounds__(256) void k_reduce1(const float* __restrict__ scratch,
    float* __restrict__ Mp)
{
  const int g     = blockIdx.x % 10;
  const int chunk = blockIdx.x / 10;
  const int idx   = chunk * 256 + threadIdx.x;
  const float* base = scratch + (size_t)(g*50) * 16384 + idx;
  float s[10];
  #pragma unroll
  for (int uu = 0; uu < 10; uu++) s[uu] = 0.f;
  for (int p = 0; p < 50; p += 10){
    #pragma unroll
    for (int uu = 0; uu < 10; uu++)
      s[uu] += base[(size_t)(p+uu)*16384];
  }
  float t0 = (s[0]+s[1]) + (s[2]+s[3]);
  float t1 = (s[4]+s[5]) + (s[6]+s[7]);
  Mp[(size_t)g*16384 + idx] = t0 + t1 + (s[8]+s[9]);
}

// Stage 2: 64 blocks, sum 10 -> M.
__global__ __launch_bounds__(256) void k_reduce2(const float* __restrict__ Mp,
    float* __restrict__ Mout)
{
  const int idx = blockIdx.x * 256 + threadIdx.x;
  float s = 0.f;
  #pragma unroll
  for (int g = 0; g < 10; g++) s += Mp[(size_t)g*16384 + idx];
  Mout[idx] = s;
}

// P[r,:] = W_ih[r,:]@M ; q[r] ; ig1[r]. 384 blocks x 128 threads.
__global__ __launch_bounds__(128) void k_smallP(const float* __restrict__ W_ih,
    const float* __restrict__ b_ih, const float* __restrict__ b_enc,
    const float* __restrict__ ws, const float* __restrict__ M,
    float* __restrict__ P, float* __restrict__ q, float* __restrict__ ig1)
{
  const int r = blockIdx.x, j = threadIdx.x;
  const float* wr = W_ih + (size_t)r * HIDDEN;
  float acc = 0.f;
  #pragma unroll 8
  for (int k = 0; k < HIDDEN; k++) acc += wr[k] * M[k*HIDDEN + j];
  P[(size_t)r*HIDDEN + j] = acc;
  const float wj = wr[j];
  float cj  = ws[WS_CH  + j] + ws[WS_CH  + 128 + j];
  float e1j = ws[WS_E1H + j] + ws[WS_E1H + 128 + j];
  float t0 = wj * (cj  + b_enc[j]);
  float t1 = wj * (e1j + b_enc[j]);
  __shared__ float r0[128], r1[128];
  r0[j] = t0; r1[j] = t1;
  __syncthreads();
  for (int off = 64; off > 0; off >>= 1){
    if (j < off){ r0[j] += r0[j+off]; r1[j] += r1[j+off]; }
    __syncthreads();
  }
  if (j == 0){
    q[r]   = r0[0] + b_ih[r];
    ig1[r] = r1[0] + b_ih[r];
  }
}

// Sequential recurrence: 256 threads x 3 rows/thread (rows t, t+256, t+512 of
// [P;W_hh]) as 3x64 packed f16x2 regs. The h-broadcast cost scales with WAVE
// COUNT (each thread reads all 128 h regardless of rows owned): R4's 12 waves
// = 192 ds_read_b128/step (~2300 cyc, measured); 4 waves = 64/step (~800 cyc).
// waves_per_eu(1,1): single resident block, full 512-reg budget, no spill.
__global__
__attribute__((amdgpu_flat_work_group_size(256, 256), amdgpu_waves_per_eu(1, 1)))
void k_recur(const float* __restrict__ P,
    const float* __restrict__ W_hh, const float* __restrict__ q,
    const float* __restrict__ b_n, const float* __restrict__ ig1,
    float* __restrict__ H_T)
{
  const int t  = threadIdx.x;
  const int r1 = t + 256, r2 = t + 512;
  const float* s0 = P + (size_t)t * HIDDEN;   // row t < 256: always P
  const float* s1 = (r1 < 384) ? (P + (size_t)r1 * HIDDEN)
                               : (W_hh + (size_t)(r1 - 384) * HIDDEN);
  const float* s2 = W_hh + (size_t)(r2 - 384) * HIDDEN;  // row >= 512: always W_hh
  const float q0 = q[t];
  const float q1 = (r1 < 384) ? q[r1] : 0.f;

  h2_t wa[64], wb[64], wc[64];
  {
    const float4* f0 = (const float4*)s0;
    const float4* f1 = (const float4*)s1;
    const float4* f2 = (const float4*)s2;
    #pragma unroll
    for (int j = 0; j < 32; j++){
      float4 v0 = f0[j], v1 = f1[j], v2 = f2[j];
      h2_t p;
      p.x=(half_t)v0.x; p.y=(half_t)v0.y; wa[2*j]   = p;
      p.x=(half_t)v0.z; p.y=(half_t)v0.w; wa[2*j+1] = p;
      p.x=(half_t)v1.x; p.y=(half_t)v1.y; wb[2*j]   = p;
      p.x=(half_t)v1.z; p.y=(half_t)v1.w; wb[2*j+1] = p;
      p.x=(half_t)v2.x; p.y=(half_t)v2.y; wc[2*j]   = p;
      p.x=(half_t)v2.z; p.y=(half_t)v2.w; wc[2*j+1] = p;
    }
  }

  __shared__ float h32[HIDDEN];
  __shared__ __align__(16) half_t h16[HIDDEN];
  __shared__ float z[768];
  __shared__ float bn[HIDDEN];
  if (t < HIDDEN){
    float bnv   = b_n[t];
    float reset = sigmoidf_(ig1[t]);
    float inp   = sigmoidf_(ig1[128+t]);
    float nw    = tanhf(ig1[256+t] + reset * bnv);
    float h1    = nw + inp * (0.f - nw);
    bn[t]  = bnv;
    h32[t] = h1;
    h16[t] = (half_t)h1;
    H_T[(size_t)t*HIDDEN] = h1;
  }
  __syncthreads();

  const uint4* hq = (const uint4*)h16;   // 16 x uint4 = 128 f16, broadcast reads
  for (int k = 1; k < STEPS; k++){
    float a0 = q0, a1 = 0.f;
    float b0 = q1, b1 = 0.f;
    float c0 = 0.f, c1 = 0.f;
    #pragma unroll
    for (int jj = 0; jj < 16; jj++){
      uint4 hb = hq[jj];
      h2_t h0 = __builtin_bit_cast(h2_t, hb.x);
      h2_t h1v = __builtin_bit_cast(h2_t, hb.y);
      h2_t h2v = __builtin_bit_cast(h2_t, hb.z);
      h2_t h3v = __builtin_bit_cast(h2_t, hb.w);
      a0 = __builtin_amdgcn_fdot2(wa[4*jj+0], h0,  a0, false);
      a1 = __builtin_amdgcn_fdot2(wa[4*jj+1], h1v, a1, false);
      a0 = __builtin_amdgcn_fdot2(wa[4*jj+2], h2v, a0, false);
      a1 = __builtin_amdgcn_fdot2(wa[4*jj+3], h3v, a1, false);
      b0 = __builtin_amdgcn_fdot2(wb[4*jj+0], h0,  b0, false);
      b1 = __builtin_amdgcn_fdot2(wb[4*jj+1], h1v, b1, false);
      b0 = __builtin_amdgcn_fdot2(wb[4*jj+2], h2v, b0, false);
      b1 = __builtin_amdgcn_fdot2(wb[4*jj+3], h3v, b1, false);
      c0 = __builtin_amdgcn_fdot2(wc[4*jj+0], h0,  c0, false);
      c1 = __builtin_amdgcn_fdot2(wc[4*jj+1], h1v, c1, false);
      c0 = __builtin_amdgcn_fdot2(wc[4*jj+2], h2v, c0, false);
      c1 = __builtin_amdgcn_fdot2(wc[4*jj+3], h3v, c1, false);
    }
    z[t]     = a0 + a1;
    z[t+256] = b0 + b1;
    z[t+512] = c0 + c1;
    __syncthreads();
    if (t < HIDDEN){
      float reset = sigmoidf_(z[t]       + z[384+t]);
      float inp   = sigmoidf_(z[128+t]   + z[512+t]);
      float nw    = tanhf(z[256+t] + reset*(z[640+t] + bn[t]));
      float hn    = nw + inp*(h32[t] - nw);
      H_T[(size_t)t*HIDDEN + k] = hn;
      h32[t] = hn;
      h16[t] = (half_t)hn;   // consumers read only after the barrier below
    }
    __syncthreads();
  }
}

// X[k][d] = W_dec[d,:]@h_k + b_dec[d]. One k-tile of 128 covers all 100 steps.
__global__ __launch_bounds__(256, 4) void k_decode(const float* __restrict__ W_dec,
    const float* __restrict__ b_dec, const float* __restrict__ H_T,
    float* __restrict__ out)
{
  __shared__ __align__(16) float Bs[128][132];
  const int t  = threadIdx.x;
  const int tx = t & 15, ty = t >> 4;
  const int d0 = blockIdx.x * 64;

  for (int l = t; l < 4096; l += 256){
    int j = l >> 5, g = l & 31;
    *(float4*)&Bs[j][g*4] = *(const float4*)&H_T[(size_t)j*HIDDEN + g*4];
  }
  __syncthreads();

  const int d  = d0 + tx*4;
  const int dc = (d < IDIM) ? d : 0;
  const float* A0 = W_dec + (size_t)dc * HIDDEN;
  const float* A1 = A0 + HIDDEN;
  const float* A2 = A1 + HIDDEN;
  const float* A3 = A2 + HIDDEN;

  float acc[4][8];
  #pragma unroll
  for (int p = 0; p < 4; p++)
    #pragma unroll
    for (int q = 0; q < 8; q++) acc[p][q] = 0.f;

  for (int j0 = 0; j0 < HIDDEN; j0 += 4){
    float4 a0 = *(const float4*)(A0 + j0);
    float4 a1 = *(const float4*)(A1 + j0);
    float4 a2 = *(const float4*)(A2 + j0);
    float4 a3 = *(const float4*)(A3 + j0);
    #pragma unroll
    for (int jj = 0; jj < 4; jj++){
      float4 b0 = *(const float4*)&Bs[j0+jj][ty*8];
      float4 b1 = *(const float4*)&Bs[j0+jj][ty*8+4];
      float e0 = (jj==0)?a0.x:(jj==1)?a0.y:(jj==2)?a0.z:a0.w;
      float e1 = (jj==0)?a1.x:(jj==1)?a1.y:(jj==2)?a1.z:a1.w;
      float e2 = (jj==0)?a2.x:(jj==1)?a2.y:(jj==2)?a2.z:a2.w;
      float e3 = (jj==0)?a3.x:(jj==1)?a3.y:(jj==2)?a3.z:a3.w;
      acc[0][0]+=e0*b0.x; acc[0][1]+=e0*b0.y; acc[0][2]+=e0*b0.z; acc[0][3]+=e0*b0.w;
      acc[0][4]+=e0*b1.x; acc[0][5]+=e0*b1.y; acc[0][6]+=e0*b1.z; acc[0][7]+=e0*b1.w;
      acc[1][0]+=e1*b0.x; acc[1][1]+=e1*b0.y; acc[1][2]+=e1*b0.z; acc[1][3]+=e1*b0.w;
      acc[1][4]+=e1*b1.x; acc[1][5]+=e1*b1.y; acc[1][6]+=e1*b1.z; acc[1][7]+=e1*b1.w;
      acc[2][0]+=e2*b0.x; acc[2][1]+=e2*b0.y; acc[2][2]+=e2*b0.z; acc[2][3]+=e2*b0.w;
      acc[2][4]+=e2*b1.x; acc[2][5]+=e2*b1.y; acc[2][6]+=e2*b1.z; acc[2][7]+=e2*b1.w;
      acc[3][0]+=e3*b0.x; acc[3][1]+=e3*b0.y; acc[3][2]+=e3*b0.z; acc[3][3]+=e3*b0.w;
      acc[3][4]+=e3*b1.x; acc[3][5]+=e3*b1.y; acc[3][6]+=e3*b1.z; acc[3][7]+=e3*b1.w;
    }
  }

  if (d < IDIM){
    float4 bd = *(const float4*)&b_dec[d];
    const size_t SO = (size_t)STEPS * IDIM;  // 5,000,000
    #pragma unroll
    for (int qq = 0; qq < 8; qq++){
      int k = ty*8 + qq;
      if (k < STEPS){
        float4 v = make_float4(acc[0][qq]+bd.x, acc[1][qq]+bd.y,
                               acc[2][qq]+bd.z, acc[3][qq]+bd.w);
        size_t o = (size_t)k * IDIM + d;
        *(float4*)&out[o]        = v;                       // samples
        *(float4*)&out[o + SO]   = v;                       // means
        *(float4*)&out[o + 2*SO] = make_float4(0.f,0.f,0.f,0.f); // sigmas
      }
    }
  }
}

extern "C" void kernel_launch(void* const* d_in, const int* in_sizes, int n_in,
                              void* d_out, int out_size, void* d_ws, size_t ws_size,
                              hipStream_t stream) {
  const float* x0    = (const float*)d_in[0];
  const float* W_enc = (const float*)d_in[1];
  const float* b_enc = (const float*)d_in[2];
  const float* W_ih  = (const float*)d_in[3];
  const float* W_hh  = (const float*)d_in[4];
  const float* b_ih  = (const float*)d_in[5];
  const float* b_n   = (const float*)d_in[6];
  const float* W_dec = (const float*)d_in[7];
  const float* b_dec = (const float*)d_in[8];
  (void)in_sizes; (void)n_in; (void)out_size; (void)ws_size;

  float* out = (float*)d_out;
  float* ws  = (float*)d_ws;
  float* M   = ws + WS_M;
  float* P   = ws + WS_P;
  float* q   = ws + WS_Q;
  float* ig1 = ws + WS_IG1;
  float* H_T = ws + WS_HT;
  float* scratch = out + SC_PART;  // 32 MB of d_out, dead until k_decode
  float* Mp      = out + SC_MP;    // 640 KB of d_out, ditto

  hipLaunchKernelGGL(k_encgemm, dim3(756), dim3(256), 0, stream, W_enc, W_dec, x0, b_dec, ws, scratch);
  hipLaunchKernelGGL(k_reduce1, dim3(640), dim3(256), 0, stream, scratch, Mp);
  hipLaunchKernelGGL(k_reduce2, dim3(64),  dim3(256), 0, stream, Mp, M);
  hipLaunchKernelGGL(k_smallP,  dim3(384), dim3(128), 0, stream, W_ih, b_ih, b_enc, ws, M, P, q, ig1);
  hipLaunchKernelGGL(k_recur,   dim3(1),   dim3(256), 0, stream, P, W_hh, q, b_n, ig1, H_T);
  hipLaunchKernelGGL(k_decode,  dim3(782), dim3(256), 0, stream, W_dec, b_dec, H_T, out);
}